// Round 4
// baseline (201.912 us; speedup 1.0000x reference)
//
#include <hip/hip_runtime.h>
#include <math.h>

// ---------------------------------------------------------------------------
// Fused 11-layer funnel MLP, round 4.
// 64 rows/wave (4 row-tiles): weight LDS reads amortized 2x vs round 3.
// Wide middle activations (h3 96w, h4 128w, h5 96w) are REGISTER-resident;
// the C-layout -> B-frag relayout is done with __shfl quad-permutes (no LDS).
// LDS arena holds only <=64-wide activations (8 KB/wave); weights 86 KB.
// Bias via pad columns + 1.0-generator rows (round 3). No main-loop barriers.
// ---------------------------------------------------------------------------

using bf16x8 = __attribute__((ext_vector_type(8))) short;   // 8 bf16 = 4 VGPRs
using f32x4  = __attribute__((ext_vector_type(4))) float;
using u16x8  = __attribute__((ext_vector_type(8))) unsigned short;
using u32x2  = __attribute__((ext_vector_type(2))) unsigned;
using u32x4  = __attribute__((ext_vector_type(4))) unsigned;
typedef __bf16 bf16x2_t __attribute__((ext_vector_type(2)));

namespace {
constexpr int NL = 11;
constexpr int IN_[NL]   = {15, 30, 60, 90, 120, 90, 60, 30, 15, 10, 5};
constexpr int OUT_[NL]  = {30, 60, 90, 120, 90, 60, 30, 15, 10, 5, 1};
constexpr int KP_[NL]   = {32, 32, 64, 96, 128, 96, 64, 32, 32, 32, 32};
constexpr int NP_[NL]   = {32, 64, 96, 128, 96, 64, 32, 16, 16, 16, 16};
constexpr int WOFF_[NL] = {0, 1024, 3072, 9216, 21504, 33792, 39936, 41984, 42496, 43008, 43520};
constexpr int WTOT      = 44032;   // shorts
constexpr int WAVES     = 8;
constexpr int ROWS_PER_BLOCK = 512;                   // 8 waves x 64 rows
constexpr int ARENA     = 4096;    // shorts per wave (8 KB, 64-wide x 64 rows)
constexpr int LDS_BYTES = (WTOT + WAVES * ARENA) * 2; // 153600
}

// fp32 -> bf16 RNE (staging only)
__device__ __forceinline__ unsigned short f2bf(float f) {
    unsigned u = __float_as_uint(f);
    u += 0x7fffu + ((u >> 16) & 1u);
    return (unsigned short)(u >> 16);
}

// packed fp32x2 -> bf16x2 (RNE)
__device__ __forceinline__ unsigned pk2(float a, float b) {
#if __has_builtin(__builtin_amdgcn_cvt_pk_bf16_f32)
    return __builtin_bit_cast(unsigned, __builtin_amdgcn_cvt_pk_bf16_f32(a, b));
#else
    bf16x2_t c;
    c[0] = (__bf16)a;
    c[1] = (__bf16)b;
    return __builtin_bit_cast(unsigned, c);
#endif
}

// ReLU + pack one C-tile accumulator: p[0]={m0,m1}, p[1]={m2,m3} (m=quad*4+r)
__device__ __forceinline__ u32x2 packrelu(f32x4 a) {
    u32x2 p;
    p[0] = pk2(fmaxf(a[0], 0.f), fmaxf(a[1], 0.f));
    p[1] = pk2(fmaxf(a[2], 0.f), fmaxf(a[3], 0.f));
    return p;
}

// C-layout (2 mt-tiles, packed) -> next-layer B-frag, in-register.
// Dest lane (col,q) dword d holds k=8q+2d..+1; source = packed dword (d&1) of
// mt (even: pa / odd: pb, chosen by q>=2) from lane col+16*(2*(q&1)+(d>>1)).
__device__ __forceinline__ bf16x8 xform(u32x2 pa, u32x2 pb, bool sel, int sA, int sB) {
    int a0 = __shfl((int)pa[0], sA);
    int b0 = __shfl((int)pb[0], sA);
    int a1 = __shfl((int)pa[1], sA);
    int b1 = __shfl((int)pb[1], sA);
    int a2 = __shfl((int)pa[0], sB);
    int b2 = __shfl((int)pb[0], sB);
    int a3 = __shfl((int)pa[1], sB);
    int b3 = __shfl((int)pb[1], sB);
    u32x4 r;
    r[0] = (unsigned)(sel ? b0 : a0);
    r[1] = (unsigned)(sel ? b1 : a1);
    r[2] = (unsigned)(sel ? b2 : a2);
    r[3] = (unsigned)(sel ? b3 : a3);
    return __builtin_bit_cast(bf16x8, r);
}

// Stage layer L's weights (A-frag-major) with bias cols / 1.0-generator rows.
template <int L>
__device__ __forceinline__ void stage_w(const float* __restrict__ W,
                                        const float* __restrict__ B,
                                        short* wlds, int tid) {
    constexpr int KP = KP_[L], NP = NP_[L], INl = IN_[L], OUTl = OUT_[L];
    constexpr int NKT = KP / 32;
    for (int idx = tid; idx < NP * KP; idx += 512) {
        const int f    = idx >> 9;
        const int t    = idx & 511;
        const int quad = t >> 7;
        const int colc = (t >> 3) & 15;
        const int j    = t & 7;
        const int mt   = f / NKT;
        const int kt   = f - mt * NKT;
        const int m    = mt * 16 + colc;
        const int k    = kt * 32 + quad * 8 + j;
        float v = 0.f;
        if (m < OUTl) {
            if (k < INl) v = W[m * INl + k];
            else if (k == INl) v = B[m];                    // bias_hi
            else if (k == INl + 1) {                        // bias_lo
                float hf = __builtin_bit_cast(float, (unsigned)f2bf(B[m]) << 16);
                v = B[m] - hf;
            }
        } else if (m == OUTl || m == OUTl + 1) {
            if (k == INl) v = 1.f;                          // 1.0-generator row
        }
        wlds[WOFF_[L] + idx] = (short)f2bf(v);
    }
}

// LDS->LDS layer over 4 row-tiles, in place (all b-frags preloaded first).
template <int L>
__device__ __forceinline__ void layer_lds(const short* __restrict__ wlds,
                                          short* buf, int col, int quad, int fo) {
    constexpr int NKT  = KP_[L] / 32;
    constexpr int NMT  = NP_[L] / 16;
    constexpr int NKTN = KP_[L + 1] / 32;
    const short* wl = wlds + WOFF_[L];
    bf16x8 bin[4][NKT];
#pragma unroll
    for (int t = 0; t < 4; ++t)
#pragma unroll
        for (int kt = 0; kt < NKT; ++kt)
            bin[t][kt] = *(const bf16x8*)(buf + (t * NKT + kt) * 512 + fo);
    f32x4 acc[NMT][4];
#pragma unroll
    for (int mt = 0; mt < NMT; ++mt)
#pragma unroll
        for (int t = 0; t < 4; ++t)
            acc[mt][t] = f32x4{0.f, 0.f, 0.f, 0.f};
#pragma unroll
    for (int kt = 0; kt < NKT; ++kt)
#pragma unroll
        for (int mt = 0; mt < NMT; ++mt) {
            bf16x8 af = *(const bf16x8*)(wl + (mt * NKT + kt) * 512 + fo);
#pragma unroll
            for (int t = 0; t < 4; ++t)
                acc[mt][t] = __builtin_amdgcn_mfma_f32_16x16x32_bf16(af, bin[t][kt], acc[mt][t], 0, 0, 0);
        }
#pragma unroll
    for (int mt = 0; mt < NMT; ++mt) {
        const int wbase = (mt >> 1) * 512 + ((mt & 1) * 2 + (quad >> 1)) * 128 + col * 8 + (quad & 1) * 4;
#pragma unroll
        for (int t = 0; t < 4; ++t)
            *(u32x2*)(buf + t * NKTN * 512 + wbase) = packrelu(acc[mt][t]);
    }
}

// Register layer, one mt-pair g: bin (all k-frags, 4 tiles) -> bout (frag g).
template <int L>
__device__ __forceinline__ void reg_pair(const short* __restrict__ wlds, int g,
                                         const bf16x8 (&bin)[KP_[L] / 32][4],
                                         bf16x8 (&bout)[4],
                                         bool sel, int sA, int sB, int fo) {
    constexpr int NKT = KP_[L] / 32;
    const short* wl = wlds + WOFF_[L];
    f32x4 acc0[4], acc1[4];
#pragma unroll
    for (int t = 0; t < 4; ++t) {
        acc0[t] = f32x4{0.f, 0.f, 0.f, 0.f};
        acc1[t] = f32x4{0.f, 0.f, 0.f, 0.f};
    }
#pragma unroll
    for (int kt = 0; kt < NKT; ++kt) {
        bf16x8 a0 = *(const bf16x8*)(wl + ((2 * g) * NKT + kt) * 512 + fo);
        bf16x8 a1 = *(const bf16x8*)(wl + ((2 * g + 1) * NKT + kt) * 512 + fo);
#pragma unroll
        for (int t = 0; t < 4; ++t) {
            acc0[t] = __builtin_amdgcn_mfma_f32_16x16x32_bf16(a0, bin[kt][t], acc0[t], 0, 0, 0);
            acc1[t] = __builtin_amdgcn_mfma_f32_16x16x32_bf16(a1, bin[kt][t], acc1[t], 0, 0, 0);
        }
    }
#pragma unroll
    for (int t = 0; t < 4; ++t)
        bout[t] = xform(packrelu(acc0[t]), packrelu(acc1[t]), sel, sA, sB);
}

// L5: h5 (regs, 96w) -> h6 (LDS, 64w) via standard C-layout epilogue.
__device__ __forceinline__ void l5_to_lds(const short* __restrict__ wlds,
                                          const bf16x8 (&h5)[3][4],
                                          short* buf, int col, int quad, int fo) {
    const short* wl = wlds + WOFF_[5];
    f32x4 acc[4][4];
#pragma unroll
    for (int mt = 0; mt < 4; ++mt)
#pragma unroll
        for (int t = 0; t < 4; ++t)
            acc[mt][t] = f32x4{0.f, 0.f, 0.f, 0.f};
#pragma unroll
    for (int kt = 0; kt < 3; ++kt)
#pragma unroll
        for (int mt = 0; mt < 4; ++mt) {
            bf16x8 af = *(const bf16x8*)(wl + (mt * 3 + kt) * 512 + fo);
#pragma unroll
            for (int t = 0; t < 4; ++t)
                acc[mt][t] = __builtin_amdgcn_mfma_f32_16x16x32_bf16(af, h5[kt][t], acc[mt][t], 0, 0, 0);
        }
#pragma unroll
    for (int mt = 0; mt < 4; ++mt) {
        const int wbase = (mt >> 1) * 512 + ((mt & 1) * 2 + (quad >> 1)) * 128 + col * 8 + (quad & 1) * 4;
#pragma unroll
        for (int t = 0; t < 4; ++t)
            *(u32x2*)(buf + t * 2 * 512 + wbase) = packrelu(acc[mt][t]);   // NKTN=2
    }
}

// 32->16 tail layer (cached weight frag), 4 tiles, in place, pad-fill k>=16.
__device__ __forceinline__ void layer_one4(bf16x8 af, short* buf, int col, int quad, int fo) {
    bf16x8 b[4];
#pragma unroll
    for (int t = 0; t < 4; ++t) b[t] = *(const bf16x8*)(buf + t * 512 + fo);
    f32x4 a[4];
#pragma unroll
    for (int t = 0; t < 4; ++t) {
        a[t] = f32x4{0.f, 0.f, 0.f, 0.f};
        a[t] = __builtin_amdgcn_mfma_f32_16x16x32_bf16(af, b[t], a[t], 0, 0, 0);
    }
    const int wbase = (quad >> 1) * 128 + col * 8 + (quad & 1) * 4;
#pragma unroll
    for (int t = 0; t < 4; ++t)
        *(u32x2*)(buf + t * 512 + wbase) = packrelu(a[t]);
    u16x8 z = {0, 0, 0, 0, 0, 0, 0, 0};
    if (!(quad & 1)) z[0] = (unsigned short)0x3F80;   // 1.0 at k==16 (bias_lo)
    *(u16x8*)(buf + (quad >> 1) * 512 + (2 + (quad & 1)) * 128 + col * 8) = z;
    *(u16x8*)(buf + ((quad >> 1) + 2) * 512 + (2 + (quad & 1)) * 128 + col * 8) = z;
}

__device__ __forceinline__ float4 ld4(const float* p) {
    float4 t;
    __builtin_memcpy(&t, p, 16);
    return t;
}

__device__ __forceinline__ void fetch_x4(const float* __restrict__ x, int row0,
                                         int col, int quad, float4 (&xv)[4]) {
#pragma unroll
    for (int t = 0; t < 4; ++t) {
        const float* xr = x + (long)(row0 + t * 16 + col) * 15;
        if (quad < 3) {
            xv[t] = ld4(xr + quad * 4);
        } else {
            float4 u = ld4(xr + 11);                 // k=12..14, then 1.0 at k=15
            xv[t] = make_float4(u.y, u.z, u.w, 1.f);
        }
    }
}

__device__ __forceinline__ void stage_x4(short* buf, const float4 (&xv)[4],
                                         int col, int quad) {
    const int off = (quad >> 1) * 128 + col * 8 + (quad & 1) * 4;
#pragma unroll
    for (int t = 0; t < 4; ++t) {
        u32x2 o;
        o[0] = pk2(xv[t].x, xv[t].y);
        o[1] = pk2(xv[t].z, xv[t].w);
        *(u32x2*)(buf + t * 512 + off) = o;
    }
    u16x8 z = {0, 0, 0, 0, 0, 0, 0, 0};
    if (!(quad & 1)) z[0] = (unsigned short)0x3F80;   // 1.0 at k==16 (bias_lo)
    *(u16x8*)(buf + (quad >> 1) * 512 + (2 + (quad & 1)) * 128 + col * 8) = z;
    *(u16x8*)(buf + ((quad >> 1) + 2) * 512 + (2 + (quad & 1)) * 128 + col * 8) = z;
}

extern "C" __global__ void __launch_bounds__(512, 2)
mlp_fused(const float* __restrict__ x,
          const float* __restrict__ W0,  const float* __restrict__ B0,
          const float* __restrict__ W1,  const float* __restrict__ B1,
          const float* __restrict__ W2,  const float* __restrict__ B2,
          const float* __restrict__ W3,  const float* __restrict__ B3,
          const float* __restrict__ W4,  const float* __restrict__ B4,
          const float* __restrict__ W5,  const float* __restrict__ B5,
          const float* __restrict__ W6,  const float* __restrict__ B6,
          const float* __restrict__ W7,  const float* __restrict__ B7,
          const float* __restrict__ W8,  const float* __restrict__ B8,
          const float* __restrict__ W9,  const float* __restrict__ B9,
          const float* __restrict__ W10, const float* __restrict__ B10,
          float* __restrict__ out, int nchunks) {
    extern __shared__ __align__(16) short smem[];
    short* wlds = smem;
    short* act  = smem + WTOT;

    const int tid = threadIdx.x;

    stage_w<0>(W0, B0, wlds, tid);
    stage_w<1>(W1, B1, wlds, tid);
    stage_w<2>(W2, B2, wlds, tid);
    stage_w<3>(W3, B3, wlds, tid);
    stage_w<4>(W4, B4, wlds, tid);
    stage_w<5>(W5, B5, wlds, tid);
    stage_w<6>(W6, B6, wlds, tid);
    stage_w<7>(W7, B7, wlds, tid);
    stage_w<8>(W8, B8, wlds, tid);
    stage_w<9>(W9, B9, wlds, tid);
    stage_w<10>(W10, B10, wlds, tid);
    __syncthreads();

    const int wave = tid >> 6;
    const int lane = tid & 63;
    const int col  = lane & 15;
    const int quad = lane >> 4;
    short* buf = act + wave * ARENA;
    const int fo = quad * 128 + col * 8;
    const bool sel = quad >= 2;
    const int sA = col + 16 * (2 * (quad & 1));
    const int sB = sA + 16;

    // Tail-layer weight frags cached in VGPRs.
    const bf16x8 w7  = *(const bf16x8*)(wlds + WOFF_[7]  + fo);
    const bf16x8 w8  = *(const bf16x8*)(wlds + WOFF_[8]  + fo);
    const bf16x8 w9  = *(const bf16x8*)(wlds + WOFF_[9]  + fo);
    const bf16x8 w10 = *(const bf16x8*)(wlds + WOFF_[10] + fo);

    int chunk = blockIdx.x;
    float4 xv[4];
    if (chunk < nchunks)
        fetch_x4(x, chunk * ROWS_PER_BLOCK + wave * 64, col, quad, xv);

    for (; chunk < nchunks; chunk += gridDim.x) {
        const int row0 = chunk * ROWS_PER_BLOCK + wave * 64;
        stage_x4(buf, xv, col, quad);

        const int nxt = chunk + gridDim.x;
        if (nxt < nchunks)
            fetch_x4(x, nxt * ROWS_PER_BLOCK + wave * 64, col, quad, xv);

        layer_lds<0>(wlds, buf, col, quad, fo);   // h0(32w) -> h1(32w)
        layer_lds<1>(wlds, buf, col, quad, fo);   // h1(32w) -> h2(64w)

        // ---- register-resident middle: L2..L4 via shfl relayout ----
        bf16x8 h2[2][4];
#pragma unroll
        for (int kt = 0; kt < 2; ++kt)
#pragma unroll
            for (int t = 0; t < 4; ++t)
                h2[kt][t] = *(const bf16x8*)(buf + (t * 2 + kt) * 512 + fo);

        bf16x8 h3[3][4];
#pragma unroll
        for (int g = 0; g < 3; ++g)
            reg_pair<2>(wlds, g, h2, h3[g], sel, sA, sB, fo);

        bf16x8 h4[4][4];
#pragma unroll
        for (int g = 0; g < 4; ++g)
            reg_pair<3>(wlds, g, h3, h4[g], sel, sA, sB, fo);

        bf16x8 h5[3][4];
#pragma unroll
        for (int g = 0; g < 3; ++g)
            reg_pair<4>(wlds, g, h4, h5[g], sel, sA, sB, fo);

        l5_to_lds(wlds, h5, buf, col, quad, fo);  // -> h6 (64w, LDS)

        layer_lds<6>(wlds, buf, col, quad, fo);   // h6(64w) -> h7(32w)
        layer_one4(w7, buf, col, quad, fo);       // 30->15
        layer_one4(w8, buf, col, quad, fo);       // 15->10
        layer_one4(w9, buf, col, quad, fo);       // 10->5

        // ---- final 5->1 + sigmoid ----
        {
            f32x4 a[4];
#pragma unroll
            for (int t = 0; t < 4; ++t) {
                bf16x8 b = *(const bf16x8*)(buf + t * 512 + fo);
                a[t] = f32x4{0.f, 0.f, 0.f, 0.f};
                a[t] = __builtin_amdgcn_mfma_f32_16x16x32_bf16(w10, b, a[t], 0, 0, 0);
            }
            if (quad == 0) {
#pragma unroll
                for (int t = 0; t < 4; ++t)
                    out[row0 + t * 16 + col] = 1.f / (1.f + __expf(-a[t][0]));
            }
        }
    }
}

extern "C" void kernel_launch(void* const* d_in, const int* in_sizes, int n_in,
                              void* d_out, int out_size, void* d_ws, size_t ws_size,
                              hipStream_t stream) {
    (void)n_in; (void)d_ws; (void)ws_size; (void)out_size;
    const float* x = (const float*)d_in[0];
    const float* W[11];
    const float* B[11];
    for (int i = 0; i < 11; ++i) {
        W[i] = (const float*)d_in[1 + 2 * i];
        B[i] = (const float*)d_in[2 + 2 * i];
    }
    const int nrows   = in_sizes[0] / 15;
    const int nchunks = nrows / ROWS_PER_BLOCK;   // 524288/512 = 1024

    hipFuncSetAttribute((const void*)mlp_fused,
                        hipFuncAttributeMaxDynamicSharedMemorySize, LDS_BYTES);

    mlp_fused<<<dim3(256), dim3(512), LDS_BYTES, stream>>>(
        x,
        W[0], B[0], W[1], B[1], W[2], B[2], W[3], B[3], W[4], B[4],
        W[5], B[5], W[6], B[6], W[7], B[7], W[8], B[8], W[9], B[9],
        W[10], B[10],
        (float*)d_out, nchunks);
}